// Round 1
// baseline (192.182 us; speedup 1.0000x reference)
//
#include <hip/hip_runtime.h>
#include <math.h>

// Problem constants (B,C,H,W) = (16,20,256,256), fp32 in, 4 fp32 scalars out.
constexpr int Bn = 16, Cn = 20, Hn = 256, Wn = 256;
constexpr int BCn = Bn * Cn;                 // 320 slices
constexpr int HWn = Hn * Wn;                 // 65536 per slice
constexpr int SPLIT = 4;                     // blocks per slice
constexpr int NBLK = BCn * SPLIT;            // 1280 blocks
constexpr int CHUNK = HWn / SPLIT;           // 16384 elems per block
constexpr int TPB = 256;
constexpr int V4_PER_THREAD = CHUNK / (TPB * 4);  // 16 float4 per thread
constexpr int NSLOT = 10;
// slots: 0 mass, 1 sum(t*y), 2 sum(t*x), 3 sum(p), 4 sum(p*y), 5 sum(p*x),
//        6 sum(p*(y^2+x^2)), 7 focal, 8 (pred-t)^2, 9 |pred|

__device__ inline float wave_reduce(float v) {
    #pragma unroll
    for (int o = 32; o > 0; o >>= 1) v += __shfl_down(v, o, 64);
    return v;
}

__global__ __launch_bounds__(TPB) void partials_kernel(
        const float* __restrict__ pred, const float* __restrict__ target,
        float* __restrict__ ws) {
    const int blk = blockIdx.x;
    const int bc = blk / SPLIT;
    const int chunk = blk % SPLIT;
    const long long base = (long long)bc * HWn + (long long)chunk * CHUNK;
    const float4* __restrict__ p4 = (const float4*)(pred + base);
    const float4* __restrict__ t4 = (const float4*)(target + base);
    const int tid = threadIdx.x;

    float acc[NSLOT];
    #pragma unroll
    for (int k = 0; k < NSLOT; k++) acc[k] = 0.f;

    const int idx0 = chunk * CHUNK;
    #pragma unroll 4
    for (int i = 0; i < V4_PER_THREAD; i++) {
        const int vec = i * TPB + tid;     // float4 index within chunk
        const float4 pv = p4[vec];
        const float4 tv = t4[vec];
        const int e0 = idx0 + vec * 4;     // element index within slice
        const float y  = (float)(e0 >> 8); // W=256; float4 never crosses a row
        const float x0 = (float)(e0 & 255);
        const float pvals[4] = {pv.x, pv.y, pv.z, pv.w};
        const float tvals[4] = {tv.x, tv.y, tv.z, tv.w};
        #pragma unroll
        for (int j = 0; j < 4; j++) {
            const float v = pvals[j];
            const float t = tvals[j];
            const float x = x0 + (float)j;
            const float p = 1.0f / (1.0f + __expf(-v));
            // focal
            const bool pos = (t == 1.0f);
            const float pt = pos ? p : 1.0f - p;
            const float at = pos ? 0.25f : 0.75f;
            const float om = 1.0f - pt;
            acc[7] -= at * om * om * __logf(pt + 1e-8f);
            // sparsity
            const float d = v - t;
            acc[8] += d * d;
            acc[9] += fabsf(v);
            // concentration partials
            acc[0] += t;
            acc[1] += t * y;
            acc[2] += t * x;
            acc[3] += p;
            acc[4] += p * y;
            acc[5] += p * x;
            acc[6] += p * (y * y + x * x);
        }
    }

    __shared__ float lds[TPB / 64][NSLOT];
    const int lane = tid & 63, wave = tid >> 6;
    #pragma unroll
    for (int k = 0; k < NSLOT; k++) {
        const float r = wave_reduce(acc[k]);
        if (lane == 0) lds[wave][k] = r;
    }
    __syncthreads();
    if (tid < NSLOT) {
        float s = 0.f;
        #pragma unroll
        for (int w = 0; w < TPB / 64; w++) s += lds[w][tid];
        ws[blk * NSLOT + tid] = s;
    }
}

__global__ __launch_bounds__(512) void finalize_kernel(
        const float* __restrict__ ws, float* __restrict__ out) {
    const int tid = threadIdx.x;

    // Per-(b,c) concentration term (threads 0..319)
    float conc_sum = 0.f, nvalid = 0.f;
    if (tid < BCn) {
        float mass = 0, sty = 0, stx = 0, sp = 0, spy = 0, spx = 0, sprr = 0;
        for (int s = 0; s < SPLIT; s++) {
            const float* w = ws + (size_t)(tid * SPLIT + s) * NSLOT;
            mass += w[0]; sty += w[1]; stx += w[2]; sp += w[3];
            spy  += w[4]; spx += w[5]; sprr += w[6];
        }
        const bool valid = mass > 0.f;
        const float sm = valid ? mass : 1.0f;
        const float cy = sty / sm, cx = stx / sm;
        const float pdsq = sprr - 2.f * cy * spy - 2.f * cx * spx
                         + (cy * cy + cx * cx) * sp;
        conc_sum = valid ? (pdsq / (float)HWn) : 0.f;   // per-sample mean
        nvalid   = valid ? 1.f : 0.f;
    }

    // Global focal / sparsity sums over all 1280 partial blocks
    float foc = 0.f, sq = 0.f, ab = 0.f;
    for (int blk = tid; blk < NBLK; blk += 512) {
        const float* w = ws + (size_t)blk * NSLOT;
        foc += w[7]; sq += w[8]; ab += w[9];
    }

    __shared__ float lds[8][5];
    const int lane = tid & 63, wave = tid >> 6;
    float vals[5] = {conc_sum, nvalid, foc, sq, ab};
    #pragma unroll
    for (int k = 0; k < 5; k++) {
        const float r = wave_reduce(vals[k]);
        if (lane == 0) lds[wave][k] = r;
    }
    __syncthreads();

    if (tid == 0) {
        float tot[5];
        #pragma unroll
        for (int k = 0; k < 5; k++) {
            float s = 0.f;
            #pragma unroll
            for (int w = 0; w < 8; w++) s += lds[w][k];
            tot[k] = s;
        }
        const float NTOT = (float)Bn * Cn * Hn * Wn;   // 20971520
        const float focal = tot[2] / NTOT;
        const float sparsity = tot[3] / NTOT + tot[4] / NTOT;
        const float concentration =
            (tot[1] > 0.f) ? (tot[0] / fmaxf(tot[1], 1.f)) : 0.f;
        const float total = 1.0f * focal + 0.8f * sparsity + 1.5f * concentration;
        out[0] = total;
        out[1] = focal;
        out[2] = sparsity;
        out[3] = concentration;
    }
}

extern "C" void kernel_launch(void* const* d_in, const int* in_sizes, int n_in,
                              void* d_out, int out_size, void* d_ws, size_t ws_size,
                              hipStream_t stream) {
    const float* pred   = (const float*)d_in[0];
    const float* target = (const float*)d_in[1];
    float* out = (float*)d_out;
    float* ws  = (float*)d_ws;   // needs NBLK*NSLOT*4 = 51.2 KB

    partials_kernel<<<NBLK, TPB, 0, stream>>>(pred, target, ws);
    finalize_kernel<<<1, 512, 0, stream>>>(ws, out);
}